// Round 16
// baseline (165.986 us; speedup 1.0000x reference)
//
#include <hip/hip_runtime.h>

#define T256 256
#define SB 1024
#define BIG 1024
#define NB 32           // hist/bucket chunks (round-15: small H beats big-H bookkeeping)
#define SEG 8           // column-scan segments (NB % SEG == 0, LB = NB/SEG = 4)
#define RANGE 6250      // bins per range-pass: counts 3125 u32 (12.5KB) + deg 25KB; cursors 25KB
#define HALF_R 3125
#define ITEMS 8         // scan1: 8192 elements per block (bsum index = g>>13)

// ================= atomic-free path =================

// grid (NB, nR): block (b,p) histograms chunk b over bin-range p.
// Packed-u16 col-counts + f32 row-deg in one pass. chunk < 65536 (u16-safe).
__global__ void __launch_bounds__(BIG)
histcd_kernel(const int* __restrict__ row, const int* __restrict__ col,
              const float* __restrict__ w, int* __restrict__ H,
              float* __restrict__ degH, int E, int N, int chunk) {
  __shared__ unsigned sc32[HALF_R];
  __shared__ float sd[RANGE];
  int b = blockIdx.x;
  int lo = blockIdx.y * RANGE;
  int hi = min(lo + RANGE, N);
  int len = hi - lo;
  long base = (long)b * chunk;
  int cnt = (int)min((long)chunk, (long)E - base);
  if (cnt < 0) cnt = 0;
  int t = threadIdx.x;
  int halfLen = (len + 1) >> 1;
  for (int i = t; i < halfLen; i += BIG) sc32[i] = 0u;
  for (int i = t; i < len; i += BIG) sd[i] = 0.f;
  __syncthreads();
  for (int i = t; i < cnt; i += BIG) {
    long e = base + i;
    int c = col[e];
    int r = row[e];
    if (c >= lo && c < hi) {
      int cc = c - lo;
      atomicAdd(&sc32[cc >> 1], 1u << ((cc & 1) << 4));   // LDS atomic, packed u16
    }
    if (r >= lo && r < hi) atomicAdd(&sd[r - lo], w[e]);  // LDS atomic
  }
  __syncthreads();
  for (int i = t; i < len; i += BIG) {
    H[(long)b * N + lo + i] = (int)((sc32[i >> 1] >> ((i & 1) << 4)) & 0xFFFFu);
    degH[(long)b * N + lo + i] = sd[i];
  }
}

// ===== segmented column scan (1568+ blocks; round-14's monolithic was 7% occupancy) =====

// grid (ceil(N/256), SEG): segment sums of H and degH
__global__ void colseg1_kernel(const int* __restrict__ H, const float* __restrict__ degH,
                               int* __restrict__ segsum, float* __restrict__ segd,
                               int N, int LB) {
  int c = blockIdx.x * blockDim.x + threadIdx.x;
  int s = blockIdx.y;
  if (c >= N) return;
  long base = (long)s * LB * N + c;
  int sum = 0;
  float d = 0.f;
  for (int j = 0; j < LB; j++) {
    sum += H[base + (long)j * N];
    d += degH[base + (long)j * N];
  }
  segsum[(long)s * N + c] = sum;
  segd[(long)s * N + c] = d;
}

// per column: exclusive scan over segments, total -> starts[c]; deg total -> disq[c]
__global__ void colseg2_kernel(int* __restrict__ segsum, const float* __restrict__ segd,
                               float* __restrict__ disq, int* __restrict__ starts, int N) {
  int c = blockIdx.x * blockDim.x + threadIdx.x;
  if (c >= N) return;
  int run = 0;
  float d = 0.f;
#pragma unroll
  for (int s = 0; s < SEG; s++) {
    long i = (long)s * N + c;
    int v = segsum[i];
    segsum[i] = run;
    run += v;
    d += segd[i];
  }
  starts[c] = run;
  disq[c] = (d > 0.f) ? rsqrtf(d) : 0.f;
}

// grid (ceil(N/256), SEG): H[b][c] -> segbase + within-segment exclusive prefix
__global__ void colseg3_kernel(int* __restrict__ H, const int* __restrict__ segsum,
                               int N, int LB) {
  int c = blockIdx.x * blockDim.x + threadIdx.x;
  int s = blockIdx.y;
  if (c >= N) return;
  int run = segsum[(long)s * N + c];
  long base = (long)s * LB * N + c;
  for (int j = 0; j < LB; j++) {
    long i = base + (long)j * N;
    int h = H[i];
    H[i] = run;
    run += h;
  }
}

// legacy monolithic column scan (fallback path, nB=1)
__global__ void colscan_kernel(int* __restrict__ H, const float* __restrict__ degH,
                               float* __restrict__ disq, int* __restrict__ cnt,
                               int N, int nB) {
  int c = blockIdx.x * blockDim.x + threadIdx.x;
  if (c >= N) return;
  int s = 0;
  float d = 0.f;
  for (int b = 0; b < nB; b++) {
    long idx = (long)b * N + c;
    int h = H[idx];
    H[idx] = s;
    s += h;
    d += degH[idx];
  }
  cnt[c] = s;
  disq[c] = (d > 0.f) ? rsqrtf(d) : 0.f;
}

// scan stage 1 over contiguous array (8192 elems/block)
__global__ void __launch_bounds__(SB)
scan1_kernel(int* __restrict__ a, int* __restrict__ bsum, int n) {
  __shared__ int s[SB];
  int t = threadIdx.x;
  int g0 = blockIdx.x * (SB * ITEMS) + t * ITEMS;
  int v[ITEMS];
  int tot = 0;
#pragma unroll
  for (int k = 0; k < ITEMS; k++) {
    int g = g0 + k;
    int u = (g < n) ? a[g] : 0;
    v[k] = u; tot += u;
  }
  s[t] = tot;
  __syncthreads();
  for (int d = 1; d < SB; d <<= 1) {
    int u = (t >= d) ? s[t - d] : 0;
    __syncthreads();
    s[t] += u;
    __syncthreads();
  }
  int run = s[t] - tot;
#pragma unroll
  for (int k = 0; k < ITEMS; k++) {
    int g = g0 + k;
    if (g < n) a[g] = run;
    run += v[k];
  }
  if (t == SB - 1) bsum[blockIdx.x] = s[SB - 1];
}

__global__ void __launch_bounds__(SB)
scan_top_kernel(int* __restrict__ bsum, int nb) {
  __shared__ int s[SB];
  int t = threadIdx.x;
  int v = (t < nb) ? bsum[t] : 0;
  s[t] = v;
  __syncthreads();
  for (int d = 1; d < SB; d <<= 1) {
    int u = (t >= d) ? s[t - d] : 0;
    __syncthreads();
    s[t] += u;
    __syncthreads();
  }
  if (t < nb) bsum[t] = s[t] - v;
}

__global__ void scan_add_kernel(int* __restrict__ a, const int* __restrict__ bsum, int n) {
  int g = blockIdx.x * blockDim.x + threadIdx.x;
  if (g < n) a[g] += bsum[g >> 13];
}

// grid (NB, nR): block (b,p) places chunk b's edges with col in range p.
// cursor base = starts[c] + H[b][c]; LDS atomics only.
__global__ void __launch_bounds__(BIG)
bucket2_kernel(const int* __restrict__ row, const int* __restrict__ col,
               const float* __restrict__ w, const float* __restrict__ disq,
               const int* __restrict__ H, const int* __restrict__ starts,
               int2* __restrict__ pairs, int E, int N, int chunk) {
  __shared__ int cur[RANGE];
  int b = blockIdx.x;
  int lo = blockIdx.y * RANGE;
  int hi = min(lo + RANGE, N);
  int len = hi - lo;
  long base = (long)b * chunk;
  int cnt = (int)min((long)chunk, (long)E - base);
  if (cnt < 0) cnt = 0;
  int t = threadIdx.x;
  for (int i = t; i < len; i += BIG)
    cur[i] = H[(long)b * N + lo + i] + starts[lo + i];
  __syncthreads();
  for (int i = t; i < cnt; i += BIG) {
    long e = base + i;
    int c = col[e];
    if (c >= lo && c < hi) {
      int r = row[e];
      float nm = -w[e] * disq[r] * disq[c];
      int pos = atomicAdd(&cur[c - lo], 1);   // LDS atomic, exclusive (b,c) ranges
      pairs[pos] = make_int2(r, __float_as_int(nm));
    }
  }
}

// ================= legacy fallback (device atomics) =================

__global__ void zero_kernel(int* __restrict__ p, long n) {
  long i = (long)blockIdx.x * blockDim.x + threadIdx.x;
  long stride = (long)gridDim.x * blockDim.x;
  for (; i < n; i += stride) p[i] = 0;
}

__global__ void deghist_dev_kernel(const float* __restrict__ w, const int* __restrict__ row,
                                   const int* __restrict__ col, float* __restrict__ deg,
                                   int* __restrict__ cntArr, int E) {
  int e = blockIdx.x * blockDim.x + threadIdx.x;
  if (e < E) {
    atomicAdd(&deg[row[e]], w[e]);
    atomicAdd(&cntArr[col[e]], 1);
  }
}

__global__ void bucket_dev_kernel(const float* __restrict__ w, const int* __restrict__ row,
                                  const int* __restrict__ col, const float* __restrict__ disq,
                                  int* __restrict__ off, int2* __restrict__ pairs, int E) {
  int e = blockIdx.x * blockDim.x + threadIdx.x;
  if (e >= E) return;
  int r = row[e], c = col[e];
  float v = -w[e] * disq[r] * disq[c];
  int p = atomicAdd(&off[c], 1);
  pairs[p] = make_int2(r, __float_as_int(v));
}

// ================= shared tail =================

// MODE 0: S[c] = start, end = S[c+1] (or E).  MODE 1: S[c] = end, start = S[c-1] (or 0).
template <int MODE>
__global__ void gather_kernel(const float* __restrict__ x, const int* __restrict__ S,
                              const int2* __restrict__ pairs, float* __restrict__ Tx,
                              int n, int E) {
  int wid = (int)(((long)blockIdx.x * blockDim.x + threadIdx.x) >> 6);
  if (wid >= n) return;
  int lane = threadIdx.x & 63;
  int slot = lane >> 3;
  int f4 = lane & 7;
  int start, end;
  if (MODE == 0) { start = S[wid]; end = (wid + 1 < n) ? S[wid + 1] : E; }
  else           { start = wid ? S[wid - 1] : 0; end = S[wid]; }
  float4 acc = make_float4(0.f, 0.f, 0.f, 0.f);
  int i = start + slot;
  for (; i + 8 < end; i += 16) {
    int2 p0 = pairs[i];
    int2 p1 = pairs[i + 8];
    float4 x0 = *(const float4*)(x + (long)p0.x * 32 + f4 * 4);
    float4 x1 = *(const float4*)(x + (long)p1.x * 32 + f4 * 4);
    float v0 = __int_as_float(p0.y);
    float v1 = __int_as_float(p1.y);
    acc.x += v0 * x0.x; acc.y += v0 * x0.y; acc.z += v0 * x0.z; acc.w += v0 * x0.w;
    acc.x += v1 * x1.x; acc.y += v1 * x1.y; acc.z += v1 * x1.z; acc.w += v1 * x1.w;
  }
  if (i < end) {
    int2 p0 = pairs[i];
    float4 x0 = *(const float4*)(x + (long)p0.x * 32 + f4 * 4);
    float v0 = __int_as_float(p0.y);
    acc.x += v0 * x0.x; acc.y += v0 * x0.y; acc.z += v0 * x0.z; acc.w += v0 * x0.w;
  }
#pragma unroll
  for (int d = 8; d < 64; d <<= 1) {
    acc.x += __shfl_xor(acc.x, d);
    acc.y += __shfl_xor(acc.y, d);
    acc.z += __shfl_xor(acc.z, d);
    acc.w += __shfl_xor(acc.w, d);
  }
  if (slot == 0) *(float4*)(Tx + (long)wid * 32 + f4 * 4) = acc;
}

// ===== fused gate: weights in LDS (allocator-proof, ~30 live VGPRs) =====
// Rounds 9-12: the allocator will not hold 64-128 per-lane weight values
// (caps at 64-84 VGPR, remats or scratch-spills in the node loop). LDS wT[m][k][33]:
// read addr lane*33+f -> bank (lane+f)%32, 2-way aliasing = free. 2 nodes/iter.
__global__ void __launch_bounds__(T256)
gate_lds_kernel(const float* __restrict__ x, const float* __restrict__ Tx,
                const float* __restrict__ Wx0, const float* __restrict__ Wx1,
                const float* __restrict__ bx, const float* __restrict__ bh,
                const float* __restrict__ Wlin, const float* __restrict__ blin,
                float* __restrict__ out, int n) {
  __shared__ float wT[4][2112];     // [m][k*33+f], m: 0=Wz0 1=Wz1 2=Wt0 3=Wt1
  __shared__ float sb[3][64];       // bz, bt, wl
  int tid = threadIdx.x;
  for (int i = tid; i < 8192; i += T256) {
    int m = i >> 11, rem = i & 2047, f = rem >> 6, k = rem & 63;
    const float* src = (m == 0) ? Wx0 : (m == 1) ? Wx1 : (m == 2) ? (Wx0 + 4096) : (Wx1 + 4096);
    wT[m][k * 33 + f] = src[f * 64 + k];
  }
  if (tid < 64) {
    sb[0][tid] = bx[tid] + bh[tid];
    sb[1][tid] = bx[128 + tid] + bh[128 + tid];
    sb[2][tid] = Wlin[tid];
  }
  __syncthreads();

  int lane = tid & 63;
  int wave = blockIdx.x * (T256 / 64) + (tid >> 6);
  int nwaves = gridDim.x * (T256 / 64);
  float bz = sb[0][lane], bt = sb[1][lane], wl = sb[2][lane], bl = blin[0];
  const float* w0 = &wT[0][lane * 33];
  const float* w1 = &wT[1][lane * 33];
  const float* w2 = &wT[2][lane * 33];
  const float* w3 = &wT[3][lane * 33];

  for (int base = wave * 2; base < n; base += nwaves * 2) {
    int node1 = base + 1;
    bool has1 = node1 < n;
    int n1 = has1 ? node1 : base;
    const float4* xp0 = (const float4*)(x + (long)base * 32);
    const float4* tp0 = (const float4*)(Tx + (long)base * 32);
    const float4* xp1 = (const float4*)(x + (long)n1 * 32);
    const float4* tp1 = (const float4*)(Tx + (long)n1 * 32);
    float az0 = bz, at0 = bt, az1 = bz, at1 = bt;
#pragma unroll
    for (int c = 0; c < 8; c++) {
      float4 xa0 = xp0[c], ta0 = tp0[c], xa1 = xp1[c], ta1 = tp1[c];
      int f = c * 4;
      float a, b2, d, g;
      a = w0[f]; b2 = w1[f]; d = w2[f]; g = w3[f];
      az0 += xa0.x * a + ta0.x * b2;  at0 += xa0.x * d + ta0.x * g;
      az1 += xa1.x * a + ta1.x * b2;  at1 += xa1.x * d + ta1.x * g;
      a = w0[f + 1]; b2 = w1[f + 1]; d = w2[f + 1]; g = w3[f + 1];
      az0 += xa0.y * a + ta0.y * b2;  at0 += xa0.y * d + ta0.y * g;
      az1 += xa1.y * a + ta1.y * b2;  at1 += xa1.y * d + ta1.y * g;
      a = w0[f + 2]; b2 = w1[f + 2]; d = w2[f + 2]; g = w3[f + 2];
      az0 += xa0.z * a + ta0.z * b2;  at0 += xa0.z * d + ta0.z * g;
      az1 += xa1.z * a + ta1.z * b2;  at1 += xa1.z * d + ta1.z * g;
      a = w0[f + 3]; b2 = w1[f + 3]; d = w2[f + 3]; g = w3[f + 3];
      az0 += xa0.w * a + ta0.w * b2;  at0 += xa0.w * d + ta0.w * g;
      az1 += xa1.w * a + ta1.w * b2;  at1 += xa1.w * d + ta1.w * g;
    }
    float c0 = __builtin_amdgcn_rcpf(1.0f + __expf(az0)) *
               (1.0f - 2.0f * __builtin_amdgcn_rcpf(__expf(2.0f * at0) + 1.0f)) * wl;
    float c1 = __builtin_amdgcn_rcpf(1.0f + __expf(az1)) *
               (1.0f - 2.0f * __builtin_amdgcn_rcpf(__expf(2.0f * at1) + 1.0f)) * wl;
#pragma unroll
    for (int d = 1; d < 64; d <<= 1) {
      c0 += __shfl_xor(c0, d);
      c1 += __shfl_xor(c1, d);
    }
    if (lane == 0) {
      out[base] = c0 + bl;
      if (has1) out[node1] = c1 + bl;
    }
  }
}

extern "C" void kernel_launch(void* const* d_in, const int* in_sizes, int n_in,
                              void* d_out, int out_size, void* d_ws, size_t ws_size,
                              hipStream_t stream) {
  const float* x    = (const float*)d_in[0];
  const float* ew   = (const float*)d_in[1];
  const float* Wx0  = (const float*)d_in[2];
  const float* Wx1  = (const float*)d_in[3];
  const float* bx   = (const float*)d_in[4];
  const float* bh   = (const float*)d_in[7];
  const float* Wlin = (const float*)d_in[8];
  const float* blin = (const float*)d_in[9];
  const int*   ei   = (const int*)d_in[10];

  int N = in_sizes[0] / 32;
  int E = in_sizes[1];
  const int* row = ei;
  const int* col = ei + E;
  float* out = (float*)d_out;
  long tthreads = (long)N * 64;
  int nR = (N + RANGE - 1) / RANGE;
  int chunk = (E + NB - 1) / NB;

  // layout: [Tx 32N (segsum 8N + segd 8N alias)][disq N][starts N][bsum 1024]
  //         [H NB*N][degH∪pairs max(NB*N, 2E)]
  size_t wTx = (size_t)N * 32;
  size_t h = (size_t)NB * N;
  size_t region = h > (size_t)2 * E ? h : (size_t)2 * E;
  size_t tot = wTx + N + N + 1024 + h + region;
  bool fits = (tot * 4 <= ws_size) && (chunk <= 65535);

  if (fits) {
    float* Tx     = (float*)d_ws;
    int*   segsum = (int*)Tx;                            // SEG*N ints, dead before gather
    float* segd   = (float*)(segsum + (size_t)SEG * N);  // SEG*N floats, ditto
    float* disq   = Tx + wTx;
    int*   starts = (int*)(disq + N);
    int*   bsum   = starts + N;
    int*   H      = bsum + 1024;
    float* degH   = (float*)(H + h);                     // aliased with pairs (degH dead first)
    int2*  pairs  = (int2*)degH;

    int LB = NB / SEG;
    int nb1 = (N + SB * ITEMS - 1) / (SB * ITEMS);
    int cblocks = (N + T256 - 1) / T256;

    histcd_kernel<<<dim3(NB, nR), BIG, 0, stream>>>(row, col, ew, H, degH, E, N, chunk);
    colseg1_kernel<<<dim3(cblocks, SEG), T256, 0, stream>>>(H, degH, segsum, segd, N, LB);
    colseg2_kernel<<<cblocks, T256, 0, stream>>>(segsum, segd, disq, starts, N);
    colseg3_kernel<<<dim3(cblocks, SEG), T256, 0, stream>>>(H, segsum, N, LB);
    scan1_kernel<<<nb1, SB, 0, stream>>>(starts, bsum, N);
    scan_top_kernel<<<1, SB, 0, stream>>>(bsum, nb1);
    scan_add_kernel<<<cblocks, T256, 0, stream>>>(starts, bsum, N);
    bucket2_kernel<<<dim3(NB, nR), BIG, 0, stream>>>(row, col, ew, disq, H, starts, pairs, E, N, chunk);
    gather_kernel<0><<<(int)((tthreads + T256 - 1) / T256), T256, 0, stream>>>(
        x, starts, pairs, Tx, N, E);
    gate_lds_kernel<<<1024, T256, 0, stream>>>(x, Tx, Wx0, Wx1, bx, bh, Wlin, blin, out, N);
  } else {
    // legacy: device-scope atomics
    float* Tx     = (float*)d_ws;
    float* disq   = Tx + wTx;
    int*   starts = (int*)(disq + N);
    int*   bsum   = starts + N;
    int*   H      = bsum + 1024;                    // N counts
    float* degH   = (float*)(H + N);                // N deg
    size_t head = wTx + N + N + 1024 + N + N;
    if (head & 1) head++;
    int2* pairs = (int2*)((float*)d_ws + head);
    int nb1 = (N + SB * ITEMS - 1) / (SB * ITEMS);
    int eb = (E + T256 - 1) / T256;

    zero_kernel<<<256, T256, 0, stream>>>(H, N);
    zero_kernel<<<256, T256, 0, stream>>>((int*)degH, N);
    deghist_dev_kernel<<<eb, T256, 0, stream>>>(ew, row, col, degH, H, E);
    colscan_kernel<<<(N + T256 - 1) / T256, T256, 0, stream>>>(H, degH, disq, starts, N, 1);
    scan1_kernel<<<nb1, SB, 0, stream>>>(starts, bsum, N);
    scan_top_kernel<<<1, SB, 0, stream>>>(bsum, nb1);
    scan_add_kernel<<<(N + T256 - 1) / T256, T256, 0, stream>>>(starts, bsum, N);
    bucket_dev_kernel<<<eb, T256, 0, stream>>>(ew, row, col, disq, starts, pairs, E);
    gather_kernel<1><<<(int)((tthreads + T256 - 1) / T256), T256, 0, stream>>>(
        x, starts, pairs, Tx, N, E);
    gate_lds_kernel<<<1024, T256, 0, stream>>>(x, Tx, Wx0, Wx1, bx, bh, Wlin, blin, out, N);
  }
}

// Round 17
// 144.284 us; speedup vs baseline: 1.1504x; 1.1504x over previous
//
#include <hip/hip_runtime.h>

#define T256 256
#define SB 1024
#define BIG 1024
#define SEG 8           // column-scan segments (nB % SEG == 0)
#define RANGE_C 25000   // histc bins/pass (u16-packed: 12500 u32 = 50 KB LDS), 2 passes
#define HALF_C 12500
#define RANGE_D 25000   // deg f32 bins/pass: 100 KB LDS, 2 passes
#define RANGE_B 25000   // bucket cursors/pass: 100 KB LDS, 2 passes
#define ITEMS 8         // scan1 (legacy): 8192 elements per block

// ================= atomic-free path (round-15 geometry: nB=128, 2 range passes) =================

// grid (nB, nRC): packed-u16 count histogram of col over range p (chunk <= 65535)
__global__ void __launch_bounds__(BIG)
histc_kernel(const int* __restrict__ col, int* __restrict__ H, int E, int N, int chunk) {
  __shared__ unsigned sc32[HALF_C];
  int b = blockIdx.x;
  int lo = blockIdx.y * RANGE_C;
  int hi = min(lo + RANGE_C, N);
  int len = hi - lo;
  long base = (long)b * chunk;
  int cnt = (int)min((long)chunk, (long)E - base);
  if (cnt < 0) cnt = 0;
  int t = threadIdx.x;
  int halfLen = (len + 1) >> 1;
  for (int i = t; i < halfLen; i += BIG) sc32[i] = 0u;
  __syncthreads();
  for (int i = t; i < cnt; i += BIG) {
    int c = col[base + i];
    if (c >= lo && c < hi) {
      int cc = c - lo;
      atomicAdd(&sc32[cc >> 1], 1u << ((cc & 1) << 4));   // LDS atomic, packed u16
    }
  }
  __syncthreads();
  for (int i = t; i < len; i += BIG)
    H[(long)b * N + lo + i] = (int)((sc32[i >> 1] >> ((i & 1) << 4)) & 0xFFFFu);
}

// grid (nB, nRD): f32 weighted histogram of row
__global__ void __launch_bounds__(BIG)
histd_kernel(const int* __restrict__ row, const float* __restrict__ w,
             float* __restrict__ degH, int E, int N, int chunk) {
  __shared__ float sd[RANGE_D];
  int b = blockIdx.x;
  int lo = blockIdx.y * RANGE_D;
  int hi = min(lo + RANGE_D, N);
  int len = hi - lo;
  long base = (long)b * chunk;
  int cnt = (int)min((long)chunk, (long)E - base);
  if (cnt < 0) cnt = 0;
  int t = threadIdx.x;
  for (int i = t; i < len; i += BIG) sd[i] = 0.f;
  __syncthreads();
  for (int i = t; i < cnt; i += BIG) {
    long e = base + i;
    int r = row[e];
    if (r >= lo && r < hi) atomicAdd(&sd[r - lo], w[e]);   // LDS atomic
  }
  __syncthreads();
  for (int i = t; i < len; i += BIG) degH[(long)b * N + lo + i] = sd[i];
}

// grid (ceil(N/256), SEG): segment sums of H and degH
__global__ void colseg1_kernel(const int* __restrict__ H, const float* __restrict__ degH,
                               int* __restrict__ segsum, float* __restrict__ segd,
                               int N, int LB) {
  int c = blockIdx.x * blockDim.x + threadIdx.x;
  int s = blockIdx.y;
  if (c >= N) return;
  long base = (long)s * LB * N + c;
  int sum = 0;
  float d = 0.f;
  for (int j = 0; j < LB; j++) {
    sum += H[base + (long)j * N];
    d += degH[base + (long)j * N];
  }
  segsum[(long)s * N + c] = sum;
  segd[(long)s * N + c] = d;
}

// per column: exclusive seg-scan (segsum in place); col total -> LDS block-scan ->
// startsLoc[c] (block-local exclusive) + bsum[block]; fused disq.
__global__ void __launch_bounds__(T256)
colseg2b_kernel(int* __restrict__ segsum, const float* __restrict__ segd,
                float* __restrict__ disq, int* __restrict__ startsLoc,
                int* __restrict__ bsum, int N) {
  __shared__ int sc[T256];
  int t = threadIdx.x;
  int c = blockIdx.x * T256 + t;
  int run = 0;
  float d = 0.f;
  if (c < N) {
#pragma unroll
    for (int s = 0; s < SEG; s++) {
      long i = (long)s * N + c;
      int v = segsum[i];
      segsum[i] = run;
      run += v;
      d += segd[i];
    }
  }
  sc[t] = run;
  __syncthreads();
  for (int dd = 1; dd < T256; dd <<= 1) {
    int u = (t >= dd) ? sc[t - dd] : 0;
    __syncthreads();
    sc[t] += u;
    __syncthreads();
  }
  if (c < N) {
    startsLoc[c] = sc[t] - run;                 // exclusive within block
    disq[c] = (d > 0.f) ? rsqrtf(d) : 0.f;
  }
  if (t == T256 - 1) bsum[blockIdx.x] = sc[t];  // block total
}

// 1 block: exclusive scan of block totals (nb <= 1024)
__global__ void __launch_bounds__(SB)
scan_top_kernel(int* __restrict__ bsum, int nb) {
  __shared__ int s[SB];
  int t = threadIdx.x;
  int v = (t < nb) ? bsum[t] : 0;
  s[t] = v;
  __syncthreads();
  for (int d = 1; d < SB; d <<= 1) {
    int u = (t >= d) ? s[t - d] : 0;
    __syncthreads();
    s[t] += u;
    __syncthreads();
  }
  if (t < nb) bsum[t] = s[t] - v;
}

// grid (ceil(N/256), SEG): H[b][c] -> GLOBAL bucket base (segbase + local prefix +
// startsLoc + bsum). After this, H row 0 = global start of each column's bucket.
__global__ void colseg3b_kernel(int* __restrict__ H, const int* __restrict__ segsum,
                                const int* __restrict__ startsLoc, const int* __restrict__ bsum,
                                int N, int LB) {
  int c = blockIdx.x * blockDim.x + threadIdx.x;
  int s = blockIdx.y;
  if (c >= N) return;
  int run = segsum[(long)s * N + c] + startsLoc[c] + bsum[c >> 8];
  long base = (long)s * LB * N + c;
  for (int j = 0; j < LB; j++) {
    long i = base + (long)j * N;
    int h = H[i];
    H[i] = run;
    run += h;
  }
}

// grid (nB, nRB): block (b,p) places chunk b's edges with col in range p.
// cursor = H[b][c] (already globally based); LDS atomics only.
__global__ void __launch_bounds__(BIG)
bucket2_kernel(const int* __restrict__ row, const int* __restrict__ col,
               const float* __restrict__ w, const float* __restrict__ disq,
               const int* __restrict__ H, int2* __restrict__ pairs,
               int E, int N, int chunk) {
  __shared__ int cur[RANGE_B];
  int b = blockIdx.x;
  int lo = blockIdx.y * RANGE_B;
  int hi = min(lo + RANGE_B, N);
  int len = hi - lo;
  long base = (long)b * chunk;
  int cnt = (int)min((long)chunk, (long)E - base);
  if (cnt < 0) cnt = 0;
  int t = threadIdx.x;
  for (int i = t; i < len; i += BIG)
    cur[i] = H[(long)b * N + lo + i];
  __syncthreads();
  for (int i = t; i < cnt; i += BIG) {
    long e = base + i;
    int c = col[e];
    if (c >= lo && c < hi) {
      int r = row[e];
      float nm = -w[e] * disq[r] * disq[c];
      int pos = atomicAdd(&cur[c - lo], 1);   // LDS atomic, exclusive (b,c) ranges
      pairs[pos] = make_int2(r, __float_as_int(nm));
    }
  }
}

// ================= legacy fallback (device atomics) =================

__global__ void zero_kernel(int* __restrict__ p, long n) {
  long i = (long)blockIdx.x * blockDim.x + threadIdx.x;
  long stride = (long)gridDim.x * blockDim.x;
  for (; i < n; i += stride) p[i] = 0;
}

__global__ void deghist_dev_kernel(const float* __restrict__ w, const int* __restrict__ row,
                                   const int* __restrict__ col, float* __restrict__ deg,
                                   int* __restrict__ cntArr, int E) {
  int e = blockIdx.x * blockDim.x + threadIdx.x;
  if (e < E) {
    atomicAdd(&deg[row[e]], w[e]);
    atomicAdd(&cntArr[col[e]], 1);
  }
}

__global__ void colscan_kernel(int* __restrict__ H, const float* __restrict__ degH,
                               float* __restrict__ disq, int* __restrict__ cnt,
                               int N, int nB) {
  int c = blockIdx.x * blockDim.x + threadIdx.x;
  if (c >= N) return;
  int s = 0;
  float d = 0.f;
  for (int b = 0; b < nB; b++) {
    long idx = (long)b * N + c;
    int h = H[idx];
    H[idx] = s;
    s += h;
    d += degH[idx];
  }
  cnt[c] = s;
  disq[c] = (d > 0.f) ? rsqrtf(d) : 0.f;
}

__global__ void __launch_bounds__(SB)
scan1_kernel(int* __restrict__ a, int* __restrict__ bsum, int n) {
  __shared__ int s[SB];
  int t = threadIdx.x;
  int g0 = blockIdx.x * (SB * ITEMS) + t * ITEMS;
  int v[ITEMS];
  int tot = 0;
#pragma unroll
  for (int k = 0; k < ITEMS; k++) {
    int g = g0 + k;
    int u = (g < n) ? a[g] : 0;
    v[k] = u; tot += u;
  }
  s[t] = tot;
  __syncthreads();
  for (int d = 1; d < SB; d <<= 1) {
    int u = (t >= d) ? s[t - d] : 0;
    __syncthreads();
    s[t] += u;
    __syncthreads();
  }
  int run = s[t] - tot;
#pragma unroll
  for (int k = 0; k < ITEMS; k++) {
    int g = g0 + k;
    if (g < n) a[g] = run;
    run += v[k];
  }
  if (t == SB - 1) bsum[blockIdx.x] = s[SB - 1];
}

__global__ void scan_add_kernel(int* __restrict__ a, const int* __restrict__ bsum, int n) {
  int g = blockIdx.x * blockDim.x + threadIdx.x;
  if (g < n) a[g] += bsum[g >> 13];
}

__global__ void bucket_dev_kernel(const float* __restrict__ w, const int* __restrict__ row,
                                  const int* __restrict__ col, const float* __restrict__ disq,
                                  int* __restrict__ off, int2* __restrict__ pairs, int E) {
  int e = blockIdx.x * blockDim.x + threadIdx.x;
  if (e >= E) return;
  int r = row[e], c = col[e];
  float v = -w[e] * disq[r] * disq[c];
  int p = atomicAdd(&off[c], 1);
  pairs[p] = make_int2(r, __float_as_int(v));
}

// ================= shared tail =================

// MODE 0: S[c] = start, end = S[c+1] (or E).  MODE 1: S[c] = end, start = S[c-1] (or 0).
template <int MODE>
__global__ void gather_kernel(const float* __restrict__ x, const int* __restrict__ S,
                              const int2* __restrict__ pairs, float* __restrict__ Tx,
                              int n, int E) {
  int wid = (int)(((long)blockIdx.x * blockDim.x + threadIdx.x) >> 6);
  if (wid >= n) return;
  int lane = threadIdx.x & 63;
  int slot = lane >> 3;
  int f4 = lane & 7;
  int start, end;
  if (MODE == 0) { start = S[wid]; end = (wid + 1 < n) ? S[wid + 1] : E; }
  else           { start = wid ? S[wid - 1] : 0; end = S[wid]; }
  float4 acc = make_float4(0.f, 0.f, 0.f, 0.f);
  int i = start + slot;
  for (; i + 8 < end; i += 16) {
    int2 p0 = pairs[i];
    int2 p1 = pairs[i + 8];
    float4 x0 = *(const float4*)(x + (long)p0.x * 32 + f4 * 4);
    float4 x1 = *(const float4*)(x + (long)p1.x * 32 + f4 * 4);
    float v0 = __int_as_float(p0.y);
    float v1 = __int_as_float(p1.y);
    acc.x += v0 * x0.x; acc.y += v0 * x0.y; acc.z += v0 * x0.z; acc.w += v0 * x0.w;
    acc.x += v1 * x1.x; acc.y += v1 * x1.y; acc.z += v1 * x1.z; acc.w += v1 * x1.w;
  }
  if (i < end) {
    int2 p0 = pairs[i];
    float4 x0 = *(const float4*)(x + (long)p0.x * 32 + f4 * 4);
    float v0 = __int_as_float(p0.y);
    acc.x += v0 * x0.x; acc.y += v0 * x0.y; acc.z += v0 * x0.z; acc.w += v0 * x0.w;
  }
#pragma unroll
  for (int d = 8; d < 64; d <<= 1) {
    acc.x += __shfl_xor(acc.x, d);
    acc.y += __shfl_xor(acc.y, d);
    acc.z += __shfl_xor(acc.z, d);
    acc.w += __shfl_xor(acc.w, d);
  }
  if (slot == 0) *(float4*)(Tx + (long)wid * 32 + f4 * 4) = acc;
}

// ===== fused gate: weights in LDS (allocator-proof; rounds 9-12: allocator won't
// hold 64-128 per-lane weights). wT[m][k][33]: bank (lane+f)%32, 2-way = free.
__global__ void __launch_bounds__(T256)
gate_lds_kernel(const float* __restrict__ x, const float* __restrict__ Tx,
                const float* __restrict__ Wx0, const float* __restrict__ Wx1,
                const float* __restrict__ bx, const float* __restrict__ bh,
                const float* __restrict__ Wlin, const float* __restrict__ blin,
                float* __restrict__ out, int n) {
  __shared__ float wT[4][2112];
  __shared__ float sb[3][64];
  int tid = threadIdx.x;
  for (int i = tid; i < 8192; i += T256) {
    int m = i >> 11, rem = i & 2047, f = rem >> 6, k = rem & 63;
    const float* src = (m == 0) ? Wx0 : (m == 1) ? Wx1 : (m == 2) ? (Wx0 + 4096) : (Wx1 + 4096);
    wT[m][k * 33 + f] = src[f * 64 + k];
  }
  if (tid < 64) {
    sb[0][tid] = bx[tid] + bh[tid];
    sb[1][tid] = bx[128 + tid] + bh[128 + tid];
    sb[2][tid] = Wlin[tid];
  }
  __syncthreads();

  int lane = tid & 63;
  int wave = blockIdx.x * (T256 / 64) + (tid >> 6);
  int nwaves = gridDim.x * (T256 / 64);
  float bz = sb[0][lane], bt = sb[1][lane], wl = sb[2][lane], bl = blin[0];
  const float* w0 = &wT[0][lane * 33];
  const float* w1 = &wT[1][lane * 33];
  const float* w2 = &wT[2][lane * 33];
  const float* w3 = &wT[3][lane * 33];

  for (int base = wave * 2; base < n; base += nwaves * 2) {
    int node1 = base + 1;
    bool has1 = node1 < n;
    int n1 = has1 ? node1 : base;
    const float4* xp0 = (const float4*)(x + (long)base * 32);
    const float4* tp0 = (const float4*)(Tx + (long)base * 32);
    const float4* xp1 = (const float4*)(x + (long)n1 * 32);
    const float4* tp1 = (const float4*)(Tx + (long)n1 * 32);
    float az0 = bz, at0 = bt, az1 = bz, at1 = bt;
#pragma unroll
    for (int c = 0; c < 8; c++) {
      float4 xa0 = xp0[c], ta0 = tp0[c], xa1 = xp1[c], ta1 = tp1[c];
      int f = c * 4;
      float a, b2, d, g;
      a = w0[f]; b2 = w1[f]; d = w2[f]; g = w3[f];
      az0 += xa0.x * a + ta0.x * b2;  at0 += xa0.x * d + ta0.x * g;
      az1 += xa1.x * a + ta1.x * b2;  at1 += xa1.x * d + ta1.x * g;
      a = w0[f + 1]; b2 = w1[f + 1]; d = w2[f + 1]; g = w3[f + 1];
      az0 += xa0.y * a + ta0.y * b2;  at0 += xa0.y * d + ta0.y * g;
      az1 += xa1.y * a + ta1.y * b2;  at1 += xa1.y * d + ta1.y * g;
      a = w0[f + 2]; b2 = w1[f + 2]; d = w2[f + 2]; g = w3[f + 2];
      az0 += xa0.z * a + ta0.z * b2;  at0 += xa0.z * d + ta0.z * g;
      az1 += xa1.z * a + ta1.z * b2;  at1 += xa1.z * d + ta1.z * g;
      a = w0[f + 3]; b2 = w1[f + 3]; d = w2[f + 3]; g = w3[f + 3];
      az0 += xa0.w * a + ta0.w * b2;  at0 += xa0.w * d + ta0.w * g;
      az1 += xa1.w * a + ta1.w * b2;  at1 += xa1.w * d + ta1.w * g;
    }
    float c0 = __builtin_amdgcn_rcpf(1.0f + __expf(az0)) *
               (1.0f - 2.0f * __builtin_amdgcn_rcpf(__expf(2.0f * at0) + 1.0f)) * wl;
    float c1 = __builtin_amdgcn_rcpf(1.0f + __expf(az1)) *
               (1.0f - 2.0f * __builtin_amdgcn_rcpf(__expf(2.0f * at1) + 1.0f)) * wl;
#pragma unroll
    for (int d = 1; d < 64; d <<= 1) {
      c0 += __shfl_xor(c0, d);
      c1 += __shfl_xor(c1, d);
    }
    if (lane == 0) {
      out[base] = c0 + bl;
      if (has1) out[node1] = c1 + bl;
    }
  }
}

extern "C" void kernel_launch(void* const* d_in, const int* in_sizes, int n_in,
                              void* d_out, int out_size, void* d_ws, size_t ws_size,
                              hipStream_t stream) {
  const float* x    = (const float*)d_in[0];
  const float* ew   = (const float*)d_in[1];
  const float* Wx0  = (const float*)d_in[2];
  const float* Wx1  = (const float*)d_in[3];
  const float* bx   = (const float*)d_in[4];
  const float* bh   = (const float*)d_in[7];
  const float* Wlin = (const float*)d_in[8];
  const float* blin = (const float*)d_in[9];
  const int*   ei   = (const int*)d_in[10];

  int N = in_sizes[0] / 32;
  int E = in_sizes[1];
  const int* row = ei;
  const int* col = ei + E;
  float* out = (float*)d_out;
  long tthreads = (long)N * 64;
  int nRC = (N + RANGE_C - 1) / RANGE_C;
  int nRD = (N + RANGE_D - 1) / RANGE_D;
  int nRB = (N + RANGE_B - 1) / RANGE_B;

  // layout: [Tx 32N (segsum 8N + segd 8N alias)][disq N][startsLoc N][bsum 1024]
  //         [H nB*N][degH∪pairs max(nB*N, 2E)]
  int nBopts[3] = {128, 96, 64};
  int nB = 0;
  size_t wTx = (size_t)N * 32;
  for (int k = 0; k < 3; k++) {
    size_t cb = (size_t)nBopts[k];
    if ((size_t)(E + nBopts[k] - 1) / nBopts[k] > 65535) continue;
    size_t h = cb * N;
    size_t region = h > (size_t)2 * E ? h : (size_t)2 * E;
    size_t tot = wTx + N + N + 1024 + h + region;
    if (tot * 4 <= ws_size) { nB = nBopts[k]; break; }
  }

  if (nB > 0) {
    float* Tx     = (float*)d_ws;
    int*   segsum = (int*)Tx;                            // SEG*N ints, dead before gather
    float* segd   = (float*)(segsum + (size_t)SEG * N);  // SEG*N floats, ditto
    float* disq   = Tx + wTx;
    int*   startsLoc = (int*)(disq + N);
    int*   bsum   = startsLoc + N;
    int*   H      = bsum + 1024;
    float* degH   = (float*)(H + (size_t)nB * N);        // aliased with pairs
    int2*  pairs  = (int2*)degH;

    int chunk = (E + nB - 1) / nB;
    int LB = nB / SEG;
    int cblocks = (N + T256 - 1) / T256;

    histc_kernel<<<dim3(nB, nRC), BIG, 0, stream>>>(col, H, E, N, chunk);
    histd_kernel<<<dim3(nB, nRD), BIG, 0, stream>>>(row, ew, degH, E, N, chunk);
    colseg1_kernel<<<dim3(cblocks, SEG), T256, 0, stream>>>(H, degH, segsum, segd, N, LB);
    colseg2b_kernel<<<cblocks, T256, 0, stream>>>(segsum, segd, disq, startsLoc, bsum, N);
    scan_top_kernel<<<1, SB, 0, stream>>>(bsum, cblocks);
    colseg3b_kernel<<<dim3(cblocks, SEG), T256, 0, stream>>>(H, segsum, startsLoc, bsum, N, LB);
    bucket2_kernel<<<dim3(nB, nRB), BIG, 0, stream>>>(row, col, ew, disq, H, pairs, E, N, chunk);
    // H row 0 now holds the GLOBAL start of each column's bucket
    gather_kernel<0><<<(int)((tthreads + T256 - 1) / T256), T256, 0, stream>>>(
        x, H, pairs, Tx, N, E);
    gate_lds_kernel<<<1024, T256, 0, stream>>>(x, Tx, Wx0, Wx1, bx, bh, Wlin, blin, out, N);
  } else {
    // legacy: device-scope atomics
    float* Tx     = (float*)d_ws;
    float* disq   = Tx + wTx;
    int*   starts = (int*)(disq + N);
    int*   bsum   = starts + N;
    int*   H      = bsum + 1024;                    // N counts
    float* degH   = (float*)(H + N);                // N deg
    size_t head = wTx + N + N + 1024 + N + N;
    if (head & 1) head++;
    int2* pairs = (int2*)((float*)d_ws + head);
    int nb1 = (N + SB * ITEMS - 1) / (SB * ITEMS);
    int eb = (E + T256 - 1) / T256;

    zero_kernel<<<256, T256, 0, stream>>>(H, N);
    zero_kernel<<<256, T256, 0, stream>>>((int*)degH, N);
    deghist_dev_kernel<<<eb, T256, 0, stream>>>(ew, row, col, degH, H, E);
    colscan_kernel<<<(N + T256 - 1) / T256, T256, 0, stream>>>(H, degH, disq, starts, N, 1);
    scan1_kernel<<<nb1, SB, 0, stream>>>(starts, bsum, N);
    scan_top_kernel<<<1, SB, 0, stream>>>(bsum, nb1);
    scan_add_kernel<<<(N + T256 - 1) / T256, T256, 0, stream>>>(starts, bsum, N);
    bucket_dev_kernel<<<eb, T256, 0, stream>>>(ew, row, col, disq, starts, pairs, E);
    gather_kernel<1><<<(int)((tthreads + T256 - 1) / T256), T256, 0, stream>>>(
        x, starts, pairs, Tx, N, E);
    gate_lds_kernel<<<1024, T256, 0, stream>>>(x, Tx, Wx0, Wx1, bx, bh, Wlin, blin, out, N);
  }
}

// Round 18
// 140.275 us; speedup vs baseline: 1.1833x; 1.0286x over previous
//
#include <hip/hip_runtime.h>

#define T256 256
#define SB 1024
#define BIG 1024
#define SEG 8           // column-scan segments (nB % SEG == 0)
#define RANGE 25000     // bins/pass: cnt 12500 u32 (50KB) + deg 25000 f32 (100KB) = 150KB LDS
#define HALF_R 12500
#define RANGE_B 25000   // bucket cursors/pass: 100 KB LDS, 2 passes
#define ITEMS 8         // scan1 (legacy): 8192 elements per block

// ================= atomic-free path (nB=128, 2 range passes) =================

// grid (nB, nR): packed-u16 col-count + f32 row-deg histograms in ONE edge walk.
// 150KB LDS. chunk <= 65535 (u16-safe).
__global__ void __launch_bounds__(BIG)
histcd_kernel(const int* __restrict__ row, const int* __restrict__ col,
              const float* __restrict__ w, int* __restrict__ H,
              float* __restrict__ degH, int E, int N, int chunk) {
  __shared__ unsigned sc32[HALF_R];
  __shared__ float sd[RANGE];
  int b = blockIdx.x;
  int lo = blockIdx.y * RANGE;
  int hi = min(lo + RANGE, N);
  int len = hi - lo;
  long base = (long)b * chunk;
  int cnt = (int)min((long)chunk, (long)E - base);
  if (cnt < 0) cnt = 0;
  int t = threadIdx.x;
  int halfLen = (len + 1) >> 1;
  for (int i = t; i < halfLen; i += BIG) sc32[i] = 0u;
  for (int i = t; i < len; i += BIG) sd[i] = 0.f;
  __syncthreads();
  for (int i = t; i < cnt; i += BIG) {
    long e = base + i;
    int c = col[e];
    int r = row[e];
    if (c >= lo && c < hi) {
      int cc = c - lo;
      atomicAdd(&sc32[cc >> 1], 1u << ((cc & 1) << 4));   // LDS atomic, packed u16
    }
    if (r >= lo && r < hi) atomicAdd(&sd[r - lo], w[e]);  // LDS atomic
  }
  __syncthreads();
  for (int i = t; i < len; i += BIG) {
    H[(long)b * N + lo + i] = (int)((sc32[i >> 1] >> ((i & 1) << 4)) & 0xFFFFu);
    degH[(long)b * N + lo + i] = sd[i];
  }
}

// grid (ceil(N/256), SEG): segment sums of H and degH
__global__ void colseg1_kernel(const int* __restrict__ H, const float* __restrict__ degH,
                               int* __restrict__ segsum, float* __restrict__ segd,
                               int N, int LB) {
  int c = blockIdx.x * blockDim.x + threadIdx.x;
  int s = blockIdx.y;
  if (c >= N) return;
  long base = (long)s * LB * N + c;
  int sum = 0;
  float d = 0.f;
  for (int j = 0; j < LB; j++) {
    sum += H[base + (long)j * N];
    d += degH[base + (long)j * N];
  }
  segsum[(long)s * N + c] = sum;
  segd[(long)s * N + c] = d;
}

// per column: exclusive seg-scan (segsum in place); col total -> LDS block-scan ->
// startsLoc[c] (block-local exclusive) + bsum[block]; fused disq.
__global__ void __launch_bounds__(T256)
colseg2b_kernel(int* __restrict__ segsum, const float* __restrict__ segd,
                float* __restrict__ disq, int* __restrict__ startsLoc,
                int* __restrict__ bsum, int N) {
  __shared__ int sc[T256];
  int t = threadIdx.x;
  int c = blockIdx.x * T256 + t;
  int run = 0;
  float d = 0.f;
  if (c < N) {
#pragma unroll
    for (int s = 0; s < SEG; s++) {
      long i = (long)s * N + c;
      int v = segsum[i];
      segsum[i] = run;
      run += v;
      d += segd[i];
    }
  }
  sc[t] = run;
  __syncthreads();
  for (int dd = 1; dd < T256; dd <<= 1) {
    int u = (t >= dd) ? sc[t - dd] : 0;
    __syncthreads();
    sc[t] += u;
    __syncthreads();
  }
  if (c < N) {
    startsLoc[c] = sc[t] - run;                 // exclusive within block
    disq[c] = (d > 0.f) ? rsqrtf(d) : 0.f;
  }
  if (t == T256 - 1) bsum[blockIdx.x] = sc[t];  // block total
}

// 1 block: exclusive scan of block totals (nb <= 1024)
__global__ void __launch_bounds__(SB)
scan_top_kernel(int* __restrict__ bsum, int nb) {
  __shared__ int s[SB];
  int t = threadIdx.x;
  int v = (t < nb) ? bsum[t] : 0;
  s[t] = v;
  __syncthreads();
  for (int d = 1; d < SB; d <<= 1) {
    int u = (t >= d) ? s[t - d] : 0;
    __syncthreads();
    s[t] += u;
    __syncthreads();
  }
  if (t < nb) bsum[t] = s[t] - v;
}

// grid (ceil(N/256), SEG): H[b][c] -> GLOBAL bucket base. H row 0 = bucket starts.
__global__ void colseg3b_kernel(int* __restrict__ H, const int* __restrict__ segsum,
                                const int* __restrict__ startsLoc, const int* __restrict__ bsum,
                                int N, int LB) {
  int c = blockIdx.x * blockDim.x + threadIdx.x;
  int s = blockIdx.y;
  if (c >= N) return;
  int run = segsum[(long)s * N + c] + startsLoc[c] + bsum[c >> 8];
  long base = (long)s * LB * N + c;
  for (int j = 0; j < LB; j++) {
    long i = base + (long)j * N;
    int h = H[i];
    H[i] = run;
    run += h;
  }
}

// grid (nB, nRB): block (b,p) places chunk b's edges with col in range p.
// cursor = H[b][c] (globally based); LDS atomics only.
__global__ void __launch_bounds__(BIG)
bucket2_kernel(const int* __restrict__ row, const int* __restrict__ col,
               const float* __restrict__ w, const float* __restrict__ disq,
               const int* __restrict__ H, int2* __restrict__ pairs,
               int E, int N, int chunk) {
  __shared__ int cur[RANGE_B];
  int b = blockIdx.x;
  int lo = blockIdx.y * RANGE_B;
  int hi = min(lo + RANGE_B, N);
  int len = hi - lo;
  long base = (long)b * chunk;
  int cnt = (int)min((long)chunk, (long)E - base);
  if (cnt < 0) cnt = 0;
  int t = threadIdx.x;
  for (int i = t; i < len; i += BIG)
    cur[i] = H[(long)b * N + lo + i];
  __syncthreads();
  for (int i = t; i < cnt; i += BIG) {
    long e = base + i;
    int c = col[e];
    if (c >= lo && c < hi) {
      int r = row[e];
      float nm = -w[e] * disq[r] * disq[c];
      int pos = atomicAdd(&cur[c - lo], 1);   // LDS atomic, exclusive (b,c) ranges
      pairs[pos] = make_int2(r, __float_as_int(nm));
    }
  }
}

// ================= legacy fallback (device atomics) =================

__global__ void zero_kernel(int* __restrict__ p, long n) {
  long i = (long)blockIdx.x * blockDim.x + threadIdx.x;
  long stride = (long)gridDim.x * blockDim.x;
  for (; i < n; i += stride) p[i] = 0;
}

__global__ void deghist_dev_kernel(const float* __restrict__ w, const int* __restrict__ row,
                                   const int* __restrict__ col, float* __restrict__ deg,
                                   int* __restrict__ cntArr, int E) {
  int e = blockIdx.x * blockDim.x + threadIdx.x;
  if (e < E) {
    atomicAdd(&deg[row[e]], w[e]);
    atomicAdd(&cntArr[col[e]], 1);
  }
}

__global__ void colscan_kernel(int* __restrict__ H, const float* __restrict__ degH,
                               float* __restrict__ disq, int* __restrict__ cnt,
                               int N, int nB) {
  int c = blockIdx.x * blockDim.x + threadIdx.x;
  if (c >= N) return;
  int s = 0;
  float d = 0.f;
  for (int b = 0; b < nB; b++) {
    long idx = (long)b * N + c;
    int h = H[idx];
    H[idx] = s;
    s += h;
    d += degH[idx];
  }
  cnt[c] = s;
  disq[c] = (d > 0.f) ? rsqrtf(d) : 0.f;
}

__global__ void __launch_bounds__(SB)
scan1_kernel(int* __restrict__ a, int* __restrict__ bsum, int n) {
  __shared__ int s[SB];
  int t = threadIdx.x;
  int g0 = blockIdx.x * (SB * ITEMS) + t * ITEMS;
  int v[ITEMS];
  int tot = 0;
#pragma unroll
  for (int k = 0; k < ITEMS; k++) {
    int g = g0 + k;
    int u = (g < n) ? a[g] : 0;
    v[k] = u; tot += u;
  }
  s[t] = tot;
  __syncthreads();
  for (int d = 1; d < SB; d <<= 1) {
    int u = (t >= d) ? s[t - d] : 0;
    __syncthreads();
    s[t] += u;
    __syncthreads();
  }
  int run = s[t] - tot;
#pragma unroll
  for (int k = 0; k < ITEMS; k++) {
    int g = g0 + k;
    if (g < n) a[g] = run;
    run += v[k];
  }
  if (t == SB - 1) bsum[blockIdx.x] = s[SB - 1];
}

__global__ void scan_add_kernel(int* __restrict__ a, const int* __restrict__ bsum, int n) {
  int g = blockIdx.x * blockDim.x + threadIdx.x;
  if (g < n) a[g] += bsum[g >> 13];
}

__global__ void bucket_dev_kernel(const float* __restrict__ w, const int* __restrict__ row,
                                  const int* __restrict__ col, const float* __restrict__ disq,
                                  int* __restrict__ off, int2* __restrict__ pairs, int E) {
  int e = blockIdx.x * blockDim.x + threadIdx.x;
  if (e >= E) return;
  int r = row[e], c = col[e];
  float v = -w[e] * disq[r] * disq[c];
  int p = atomicAdd(&off[c], 1);
  pairs[p] = make_int2(r, __float_as_int(v));
}

// ================= shared tail =================

// MODE 0: S[c] = start, end = S[c+1] (or E).  MODE 1: S[c] = end, start = S[c-1] (or 0).
template <int MODE>
__global__ void gather_kernel(const float* __restrict__ x, const int* __restrict__ S,
                              const int2* __restrict__ pairs, float* __restrict__ Tx,
                              int n, int E) {
  int wid = (int)(((long)blockIdx.x * blockDim.x + threadIdx.x) >> 6);
  if (wid >= n) return;
  int lane = threadIdx.x & 63;
  int slot = lane >> 3;
  int f4 = lane & 7;
  int start, end;
  if (MODE == 0) { start = S[wid]; end = (wid + 1 < n) ? S[wid + 1] : E; }
  else           { start = wid ? S[wid - 1] : 0; end = S[wid]; }
  float4 acc = make_float4(0.f, 0.f, 0.f, 0.f);
  int i = start + slot;
  // 4-deep unroll: 32 edges in flight per wave
  for (; i + 24 < end; i += 32) {
    int2 p0 = pairs[i];
    int2 p1 = pairs[i + 8];
    int2 p2 = pairs[i + 16];
    int2 p3 = pairs[i + 24];
    float4 x0 = *(const float4*)(x + (long)p0.x * 32 + f4 * 4);
    float4 x1 = *(const float4*)(x + (long)p1.x * 32 + f4 * 4);
    float4 x2 = *(const float4*)(x + (long)p2.x * 32 + f4 * 4);
    float4 x3 = *(const float4*)(x + (long)p3.x * 32 + f4 * 4);
    float v0 = __int_as_float(p0.y);
    float v1 = __int_as_float(p1.y);
    float v2 = __int_as_float(p2.y);
    float v3 = __int_as_float(p3.y);
    acc.x += v0 * x0.x; acc.y += v0 * x0.y; acc.z += v0 * x0.z; acc.w += v0 * x0.w;
    acc.x += v1 * x1.x; acc.y += v1 * x1.y; acc.z += v1 * x1.z; acc.w += v1 * x1.w;
    acc.x += v2 * x2.x; acc.y += v2 * x2.y; acc.z += v2 * x2.z; acc.w += v2 * x2.w;
    acc.x += v3 * x3.x; acc.y += v3 * x3.y; acc.z += v3 * x3.z; acc.w += v3 * x3.w;
  }
  for (; i < end; i += 8) {
    int2 p0 = pairs[i];
    float4 x0 = *(const float4*)(x + (long)p0.x * 32 + f4 * 4);
    float v0 = __int_as_float(p0.y);
    acc.x += v0 * x0.x; acc.y += v0 * x0.y; acc.z += v0 * x0.z; acc.w += v0 * x0.w;
  }
#pragma unroll
  for (int d = 8; d < 64; d <<= 1) {
    acc.x += __shfl_xor(acc.x, d);
    acc.y += __shfl_xor(acc.y, d);
    acc.z += __shfl_xor(acc.z, d);
    acc.w += __shfl_xor(acc.w, d);
  }
  if (slot == 0) *(float4*)(Tx + (long)wid * 32 + f4 * 4) = acc;
}

// ===== fused gate: weights in LDS (allocator-proof; rounds 9-12: allocator won't
// hold 64-128 per-lane weights). wT[m][k][33]: bank (lane+f)%32, 2-way = free.
__global__ void __launch_bounds__(T256)
gate_lds_kernel(const float* __restrict__ x, const float* __restrict__ Tx,
                const float* __restrict__ Wx0, const float* __restrict__ Wx1,
                const float* __restrict__ bx, const float* __restrict__ bh,
                const float* __restrict__ Wlin, const float* __restrict__ blin,
                float* __restrict__ out, int n) {
  __shared__ float wT[4][2112];
  __shared__ float sb[3][64];
  int tid = threadIdx.x;
  for (int i = tid; i < 8192; i += T256) {
    int m = i >> 11, rem = i & 2047, f = rem >> 6, k = rem & 63;
    const float* src = (m == 0) ? Wx0 : (m == 1) ? Wx1 : (m == 2) ? (Wx0 + 4096) : (Wx1 + 4096);
    wT[m][k * 33 + f] = src[f * 64 + k];
  }
  if (tid < 64) {
    sb[0][tid] = bx[tid] + bh[tid];
    sb[1][tid] = bx[128 + tid] + bh[128 + tid];
    sb[2][tid] = Wlin[tid];
  }
  __syncthreads();

  int lane = tid & 63;
  int wave = blockIdx.x * (T256 / 64) + (tid >> 6);
  int nwaves = gridDim.x * (T256 / 64);
  float bz = sb[0][lane], bt = sb[1][lane], wl = sb[2][lane], bl = blin[0];
  const float* w0 = &wT[0][lane * 33];
  const float* w1 = &wT[1][lane * 33];
  const float* w2 = &wT[2][lane * 33];
  const float* w3 = &wT[3][lane * 33];

  for (int base = wave * 2; base < n; base += nwaves * 2) {
    int node1 = base + 1;
    bool has1 = node1 < n;
    int n1 = has1 ? node1 : base;
    const float4* xp0 = (const float4*)(x + (long)base * 32);
    const float4* tp0 = (const float4*)(Tx + (long)base * 32);
    const float4* xp1 = (const float4*)(x + (long)n1 * 32);
    const float4* tp1 = (const float4*)(Tx + (long)n1 * 32);
    float az0 = bz, at0 = bt, az1 = bz, at1 = bt;
#pragma unroll
    for (int c = 0; c < 8; c++) {
      float4 xa0 = xp0[c], ta0 = tp0[c], xa1 = xp1[c], ta1 = tp1[c];
      int f = c * 4;
      float a, b2, d, g;
      a = w0[f]; b2 = w1[f]; d = w2[f]; g = w3[f];
      az0 += xa0.x * a + ta0.x * b2;  at0 += xa0.x * d + ta0.x * g;
      az1 += xa1.x * a + ta1.x * b2;  at1 += xa1.x * d + ta1.x * g;
      a = w0[f + 1]; b2 = w1[f + 1]; d = w2[f + 1]; g = w3[f + 1];
      az0 += xa0.y * a + ta0.y * b2;  at0 += xa0.y * d + ta0.y * g;
      az1 += xa1.y * a + ta1.y * b2;  at1 += xa1.y * d + ta1.y * g;
      a = w0[f + 2]; b2 = w1[f + 2]; d = w2[f + 2]; g = w3[f + 2];
      az0 += xa0.z * a + ta0.z * b2;  at0 += xa0.z * d + ta0.z * g;
      az1 += xa1.z * a + ta1.z * b2;  at1 += xa1.z * d + ta1.z * g;
      a = w0[f + 3]; b2 = w1[f + 3]; d = w2[f + 3]; g = w3[f + 3];
      az0 += xa0.w * a + ta0.w * b2;  at0 += xa0.w * d + ta0.w * g;
      az1 += xa1.w * a + ta1.w * b2;  at1 += xa1.w * d + ta1.w * g;
    }
    float c0 = __builtin_amdgcn_rcpf(1.0f + __expf(az0)) *
               (1.0f - 2.0f * __builtin_amdgcn_rcpf(__expf(2.0f * at0) + 1.0f)) * wl;
    float c1 = __builtin_amdgcn_rcpf(1.0f + __expf(az1)) *
               (1.0f - 2.0f * __builtin_amdgcn_rcpf(__expf(2.0f * at1) + 1.0f)) * wl;
#pragma unroll
    for (int d = 1; d < 64; d <<= 1) {
      c0 += __shfl_xor(c0, d);
      c1 += __shfl_xor(c1, d);
    }
    if (lane == 0) {
      out[base] = c0 + bl;
      if (has1) out[node1] = c1 + bl;
    }
  }
}

extern "C" void kernel_launch(void* const* d_in, const int* in_sizes, int n_in,
                              void* d_out, int out_size, void* d_ws, size_t ws_size,
                              hipStream_t stream) {
  const float* x    = (const float*)d_in[0];
  const float* ew   = (const float*)d_in[1];
  const float* Wx0  = (const float*)d_in[2];
  const float* Wx1  = (const float*)d_in[3];
  const float* bx   = (const float*)d_in[4];
  const float* bh   = (const float*)d_in[7];
  const float* Wlin = (const float*)d_in[8];
  const float* blin = (const float*)d_in[9];
  const int*   ei   = (const int*)d_in[10];

  int N = in_sizes[0] / 32;
  int E = in_sizes[1];
  const int* row = ei;
  const int* col = ei + E;
  float* out = (float*)d_out;
  long tthreads = (long)N * 64;
  int nR = (N + RANGE - 1) / RANGE;
  int nRB = (N + RANGE_B - 1) / RANGE_B;

  // layout: [Tx 32N (segsum 8N + segd 8N alias)][disq N][startsLoc N][bsum 1024]
  //         [H nB*N][degH∪pairs max(nB*N, 2E)]
  int nBopts[3] = {128, 96, 64};
  int nB = 0;
  size_t wTx = (size_t)N * 32;
  for (int k = 0; k < 3; k++) {
    size_t cb = (size_t)nBopts[k];
    if ((size_t)(E + nBopts[k] - 1) / nBopts[k] > 65535) continue;
    size_t h = cb * N;
    size_t region = h > (size_t)2 * E ? h : (size_t)2 * E;
    size_t tot = wTx + N + N + 1024 + h + region;
    if (tot * 4 <= ws_size) { nB = nBopts[k]; break; }
  }

  if (nB > 0) {
    float* Tx     = (float*)d_ws;
    int*   segsum = (int*)Tx;                            // SEG*N ints, dead before gather
    float* segd   = (float*)(segsum + (size_t)SEG * N);  // SEG*N floats, ditto
    float* disq   = Tx + wTx;
    int*   startsLoc = (int*)(disq + N);
    int*   bsum   = startsLoc + N;
    int*   H      = bsum + 1024;
    float* degH   = (float*)(H + (size_t)nB * N);        // aliased with pairs
    int2*  pairs  = (int2*)degH;

    int chunk = (E + nB - 1) / nB;
    int LB = nB / SEG;
    int cblocks = (N + T256 - 1) / T256;

    histcd_kernel<<<dim3(nB, nR), BIG, 0, stream>>>(row, col, ew, H, degH, E, N, chunk);
    colseg1_kernel<<<dim3(cblocks, SEG), T256, 0, stream>>>(H, degH, segsum, segd, N, LB);
    colseg2b_kernel<<<cblocks, T256, 0, stream>>>(segsum, segd, disq, startsLoc, bsum, N);
    scan_top_kernel<<<1, SB, 0, stream>>>(bsum, cblocks);
    colseg3b_kernel<<<dim3(cblocks, SEG), T256, 0, stream>>>(H, segsum, startsLoc, bsum, N, LB);
    bucket2_kernel<<<dim3(nB, nRB), BIG, 0, stream>>>(row, col, ew, disq, H, pairs, E, N, chunk);
    // H row 0 now holds the GLOBAL start of each column's bucket
    gather_kernel<0><<<(int)((tthreads + T256 - 1) / T256), T256, 0, stream>>>(
        x, H, pairs, Tx, N, E);
    gate_lds_kernel<<<1024, T256, 0, stream>>>(x, Tx, Wx0, Wx1, bx, bh, Wlin, blin, out, N);
  } else {
    // legacy: device-scope atomics
    float* Tx     = (float*)d_ws;
    float* disq   = Tx + wTx;
    int*   starts = (int*)(disq + N);
    int*   bsum   = starts + N;
    int*   H      = bsum + 1024;                    // N counts
    float* degH   = (float*)(H + N);                // N deg
    size_t head = wTx + N + N + 1024 + N + N;
    if (head & 1) head++;
    int2* pairs = (int2*)((float*)d_ws + head);
    int nb1 = (N + SB * ITEMS - 1) / (SB * ITEMS);
    int eb = (E + T256 - 1) / T256;

    zero_kernel<<<256, T256, 0, stream>>>(H, N);
    zero_kernel<<<256, T256, 0, stream>>>((int*)degH, N);
    deghist_dev_kernel<<<eb, T256, 0, stream>>>(ew, row, col, degH, H, E);
    colscan_kernel<<<(N + T256 - 1) / T256, T256, 0, stream>>>(H, degH, disq, starts, N, 1);
    scan1_kernel<<<nb1, SB, 0, stream>>>(starts, bsum, N);
    scan_top_kernel<<<1, SB, 0, stream>>>(bsum, nb1);
    scan_add_kernel<<<(N + T256 - 1) / T256, T256, 0, stream>>>(starts, bsum, N);
    bucket_dev_kernel<<<eb, T256, 0, stream>>>(ew, row, col, disq, starts, pairs, E);
    gather_kernel<1><<<(int)((tthreads + T256 - 1) / T256), T256, 0, stream>>>(
        x, starts, pairs, Tx, N, E);
    gate_lds_kernel<<<1024, T256, 0, stream>>>(x, Tx, Wx0, Wx1, bx, bh, Wlin, blin, out, N);
  }
}

// Round 19
// 138.916 us; speedup vs baseline: 1.1949x; 1.0098x over previous
//
#include <hip/hip_runtime.h>
#include <hip/hip_fp16.h>

#define T256 256
#define SB 1024
#define BIG 1024
#define SEG 8           // column-scan segments (nB % SEG == 0)
#define RANGE 25000     // bins/pass: cnt 12500 u32 (50KB) + deg 25000 f32 (100KB) = 150KB LDS
#define HALF_R 12500
#define RANGE_B 25000   // bucket cursors/pass: 100 KB LDS, 2 passes
#define ITEMS 8         // scan1 (legacy): 8192 elements per block

// ================= atomic-free path (nB=128, 2 range passes) =================

// grid (nB, nR): packed-u16 col-count + f32 row-deg histograms in ONE edge walk.
// 150KB LDS. chunk <= 65535 (u16-safe).
__global__ void __launch_bounds__(BIG)
histcd_kernel(const int* __restrict__ row, const int* __restrict__ col,
              const float* __restrict__ w, int* __restrict__ H,
              float* __restrict__ degH, int E, int N, int chunk) {
  __shared__ unsigned sc32[HALF_R];
  __shared__ float sd[RANGE];
  int b = blockIdx.x;
  int lo = blockIdx.y * RANGE;
  int hi = min(lo + RANGE, N);
  int len = hi - lo;
  long base = (long)b * chunk;
  int cnt = (int)min((long)chunk, (long)E - base);
  if (cnt < 0) cnt = 0;
  int t = threadIdx.x;
  int halfLen = (len + 1) >> 1;
  for (int i = t; i < halfLen; i += BIG) sc32[i] = 0u;
  for (int i = t; i < len; i += BIG) sd[i] = 0.f;
  __syncthreads();
  for (int i = t; i < cnt; i += BIG) {
    long e = base + i;
    int c = col[e];
    int r = row[e];
    if (c >= lo && c < hi) {
      int cc = c - lo;
      atomicAdd(&sc32[cc >> 1], 1u << ((cc & 1) << 4));   // LDS atomic, packed u16
    }
    if (r >= lo && r < hi) atomicAdd(&sd[r - lo], w[e]);  // LDS atomic
  }
  __syncthreads();
  for (int i = t; i < len; i += BIG) {
    H[(long)b * N + lo + i] = (int)((sc32[i >> 1] >> ((i & 1) << 4)) & 0xFFFFu);
    degH[(long)b * N + lo + i] = sd[i];
  }
}

// grid (ceil(N/256), SEG): segment sums of H and degH
__global__ void colseg1_kernel(const int* __restrict__ H, const float* __restrict__ degH,
                               int* __restrict__ segsum, float* __restrict__ segd,
                               int N, int LB) {
  int c = blockIdx.x * blockDim.x + threadIdx.x;
  int s = blockIdx.y;
  if (c >= N) return;
  long base = (long)s * LB * N + c;
  int sum = 0;
  float d = 0.f;
  for (int j = 0; j < LB; j++) {
    sum += H[base + (long)j * N];
    d += degH[base + (long)j * N];
  }
  segsum[(long)s * N + c] = sum;
  segd[(long)s * N + c] = d;
}

// per column: exclusive seg-scan (segsum in place); col total -> LDS block-scan ->
// startsLoc[c] (block-local exclusive) + bsum[block]; fused disq.
__global__ void __launch_bounds__(T256)
colseg2b_kernel(int* __restrict__ segsum, const float* __restrict__ segd,
                float* __restrict__ disq, int* __restrict__ startsLoc,
                int* __restrict__ bsum, int N) {
  __shared__ int sc[T256];
  int t = threadIdx.x;
  int c = blockIdx.x * T256 + t;
  int run = 0;
  float d = 0.f;
  if (c < N) {
#pragma unroll
    for (int s = 0; s < SEG; s++) {
      long i = (long)s * N + c;
      int v = segsum[i];
      segsum[i] = run;
      run += v;
      d += segd[i];
    }
  }
  sc[t] = run;
  __syncthreads();
  for (int dd = 1; dd < T256; dd <<= 1) {
    int u = (t >= dd) ? sc[t - dd] : 0;
    __syncthreads();
    sc[t] += u;
    __syncthreads();
  }
  if (c < N) {
    startsLoc[c] = sc[t] - run;                 // exclusive within block
    disq[c] = (d > 0.f) ? rsqrtf(d) : 0.f;
  }
  if (t == T256 - 1) bsum[blockIdx.x] = sc[t];  // block total
}

// 1 block: exclusive scan of block totals (nb <= 1024)
__global__ void __launch_bounds__(SB)
scan_top_kernel(int* __restrict__ bsum, int nb) {
  __shared__ int s[SB];
  int t = threadIdx.x;
  int v = (t < nb) ? bsum[t] : 0;
  s[t] = v;
  __syncthreads();
  for (int d = 1; d < SB; d <<= 1) {
    int u = (t >= d) ? s[t - d] : 0;
    __syncthreads();
    s[t] += u;
    __syncthreads();
  }
  if (t < nb) bsum[t] = s[t] - v;
}

// grid (ceil(N/256), SEG): H[b][c] -> GLOBAL bucket base. H row 0 = bucket starts.
__global__ void colseg3b_kernel(int* __restrict__ H, const int* __restrict__ segsum,
                                const int* __restrict__ startsLoc, const int* __restrict__ bsum,
                                int N, int LB) {
  int c = blockIdx.x * blockDim.x + threadIdx.x;
  int s = blockIdx.y;
  if (c >= N) return;
  int run = segsum[(long)s * N + c] + startsLoc[c] + bsum[c >> 8];
  long base = (long)s * LB * N + c;
  for (int j = 0; j < LB; j++) {
    long i = base + (long)j * N;
    int h = H[i];
    H[i] = run;
    run += h;
  }
}

// grid (nB, nRB): block (b,p) places chunk b's edges with col in range p.
// PACKED pairs: u32 = (row:u16 << 16) | f16(norm). Requires N <= 65536.
// cursor = H[b][c] (globally based); LDS atomics only.
__global__ void __launch_bounds__(BIG)
bucket2p_kernel(const int* __restrict__ row, const int* __restrict__ col,
                const float* __restrict__ w, const float* __restrict__ disq,
                const int* __restrict__ H, unsigned* __restrict__ pairs32,
                int E, int N, int chunk) {
  __shared__ int cur[RANGE_B];
  int b = blockIdx.x;
  int lo = blockIdx.y * RANGE_B;
  int hi = min(lo + RANGE_B, N);
  int len = hi - lo;
  long base = (long)b * chunk;
  int cnt = (int)min((long)chunk, (long)E - base);
  if (cnt < 0) cnt = 0;
  int t = threadIdx.x;
  for (int i = t; i < len; i += BIG)
    cur[i] = H[(long)b * N + lo + i];
  __syncthreads();
  for (int i = t; i < cnt; i += BIG) {
    long e = base + i;
    int c = col[e];
    if (c >= lo && c < hi) {
      int r = row[e];
      float nm = -w[e] * disq[r] * disq[c];
      unsigned hb = __half_as_ushort(__float2half(nm));
      unsigned packed = ((unsigned)r << 16) | hb;
      int pos = atomicAdd(&cur[c - lo], 1);   // LDS atomic, exclusive (b,c) ranges
      pairs32[pos] = packed;
    }
  }
}

// ================= legacy fallback (device atomics) =================

__global__ void zero_kernel(int* __restrict__ p, long n) {
  long i = (long)blockIdx.x * blockDim.x + threadIdx.x;
  long stride = (long)gridDim.x * blockDim.x;
  for (; i < n; i += stride) p[i] = 0;
}

__global__ void deghist_dev_kernel(const float* __restrict__ w, const int* __restrict__ row,
                                   const int* __restrict__ col, float* __restrict__ deg,
                                   int* __restrict__ cntArr, int E) {
  int e = blockIdx.x * blockDim.x + threadIdx.x;
  if (e < E) {
    atomicAdd(&deg[row[e]], w[e]);
    atomicAdd(&cntArr[col[e]], 1);
  }
}

__global__ void colscan_kernel(int* __restrict__ H, const float* __restrict__ degH,
                               float* __restrict__ disq, int* __restrict__ cnt,
                               int N, int nB) {
  int c = blockIdx.x * blockDim.x + threadIdx.x;
  if (c >= N) return;
  int s = 0;
  float d = 0.f;
  for (int b = 0; b < nB; b++) {
    long idx = (long)b * N + c;
    int h = H[idx];
    H[idx] = s;
    s += h;
    d += degH[idx];
  }
  cnt[c] = s;
  disq[c] = (d > 0.f) ? rsqrtf(d) : 0.f;
}

__global__ void __launch_bounds__(SB)
scan1_kernel(int* __restrict__ a, int* __restrict__ bsum, int n) {
  __shared__ int s[SB];
  int t = threadIdx.x;
  int g0 = blockIdx.x * (SB * ITEMS) + t * ITEMS;
  int v[ITEMS];
  int tot = 0;
#pragma unroll
  for (int k = 0; k < ITEMS; k++) {
    int g = g0 + k;
    int u = (g < n) ? a[g] : 0;
    v[k] = u; tot += u;
  }
  s[t] = tot;
  __syncthreads();
  for (int d = 1; d < SB; d <<= 1) {
    int u = (t >= d) ? s[t - d] : 0;
    __syncthreads();
    s[t] += u;
    __syncthreads();
  }
  int run = s[t] - tot;
#pragma unroll
  for (int k = 0; k < ITEMS; k++) {
    int g = g0 + k;
    if (g < n) a[g] = run;
    run += v[k];
  }
  if (t == SB - 1) bsum[blockIdx.x] = s[SB - 1];
}

__global__ void scan_add_kernel(int* __restrict__ a, const int* __restrict__ bsum, int n) {
  int g = blockIdx.x * blockDim.x + threadIdx.x;
  if (g < n) a[g] += bsum[g >> 13];
}

__global__ void bucket_dev_kernel(const float* __restrict__ w, const int* __restrict__ row,
                                  const int* __restrict__ col, const float* __restrict__ disq,
                                  int* __restrict__ off, int2* __restrict__ pairs, int E) {
  int e = blockIdx.x * blockDim.x + threadIdx.x;
  if (e >= E) return;
  int r = row[e], c = col[e];
  float v = -w[e] * disq[r] * disq[c];
  int p = atomicAdd(&off[c], 1);
  pairs[p] = make_int2(r, __float_as_int(v));
}

// ================= shared tail =================

// PACKED gather: pairs32[i] = (row:u16 << 16) | f16(norm). S[c] = start, end = S[c+1].
__global__ void gatherp_kernel(const float* __restrict__ x, const int* __restrict__ S,
                               const unsigned* __restrict__ pairs32, float* __restrict__ Tx,
                               int n, int E) {
  int wid = (int)(((long)blockIdx.x * blockDim.x + threadIdx.x) >> 6);
  if (wid >= n) return;
  int lane = threadIdx.x & 63;
  int slot = lane >> 3;
  int f4 = lane & 7;
  int start = S[wid];
  int end = (wid + 1 < n) ? S[wid + 1] : E;
  float4 acc = make_float4(0.f, 0.f, 0.f, 0.f);
  int i = start + slot;
  // 4-deep unroll: 32 edges in flight per wave
  for (; i + 24 < end; i += 32) {
    unsigned p0 = pairs32[i];
    unsigned p1 = pairs32[i + 8];
    unsigned p2 = pairs32[i + 16];
    unsigned p3 = pairs32[i + 24];
    float4 x0 = *(const float4*)(x + (long)(p0 >> 16) * 32 + f4 * 4);
    float4 x1 = *(const float4*)(x + (long)(p1 >> 16) * 32 + f4 * 4);
    float4 x2 = *(const float4*)(x + (long)(p2 >> 16) * 32 + f4 * 4);
    float4 x3 = *(const float4*)(x + (long)(p3 >> 16) * 32 + f4 * 4);
    float v0 = __half2float(__ushort_as_half((unsigned short)(p0 & 0xFFFFu)));
    float v1 = __half2float(__ushort_as_half((unsigned short)(p1 & 0xFFFFu)));
    float v2 = __half2float(__ushort_as_half((unsigned short)(p2 & 0xFFFFu)));
    float v3 = __half2float(__ushort_as_half((unsigned short)(p3 & 0xFFFFu)));
    acc.x += v0 * x0.x; acc.y += v0 * x0.y; acc.z += v0 * x0.z; acc.w += v0 * x0.w;
    acc.x += v1 * x1.x; acc.y += v1 * x1.y; acc.z += v1 * x1.z; acc.w += v1 * x1.w;
    acc.x += v2 * x2.x; acc.y += v2 * x2.y; acc.z += v2 * x2.z; acc.w += v2 * x2.w;
    acc.x += v3 * x3.x; acc.y += v3 * x3.y; acc.z += v3 * x3.z; acc.w += v3 * x3.w;
  }
  for (; i < end; i += 8) {
    unsigned p0 = pairs32[i];
    float4 x0 = *(const float4*)(x + (long)(p0 >> 16) * 32 + f4 * 4);
    float v0 = __half2float(__ushort_as_half((unsigned short)(p0 & 0xFFFFu)));
    acc.x += v0 * x0.x; acc.y += v0 * x0.y; acc.z += v0 * x0.z; acc.w += v0 * x0.w;
  }
#pragma unroll
  for (int d = 8; d < 64; d <<= 1) {
    acc.x += __shfl_xor(acc.x, d);
    acc.y += __shfl_xor(acc.y, d);
    acc.z += __shfl_xor(acc.z, d);
    acc.w += __shfl_xor(acc.w, d);
  }
  if (slot == 0) *(float4*)(Tx + (long)wid * 32 + f4 * 4) = acc;
}

// int2 gather (legacy): S[c] = end, start = S[c-1] (or 0).
__global__ void gather_kernel(const float* __restrict__ x, const int* __restrict__ S,
                              const int2* __restrict__ pairs, float* __restrict__ Tx,
                              int n, int E) {
  int wid = (int)(((long)blockIdx.x * blockDim.x + threadIdx.x) >> 6);
  if (wid >= n) return;
  int lane = threadIdx.x & 63;
  int slot = lane >> 3;
  int f4 = lane & 7;
  int start = wid ? S[wid - 1] : 0;
  int end = S[wid];
  float4 acc = make_float4(0.f, 0.f, 0.f, 0.f);
  int i = start + slot;
  for (; i + 8 < end; i += 16) {
    int2 p0 = pairs[i];
    int2 p1 = pairs[i + 8];
    float4 x0 = *(const float4*)(x + (long)p0.x * 32 + f4 * 4);
    float4 x1 = *(const float4*)(x + (long)p1.x * 32 + f4 * 4);
    float v0 = __int_as_float(p0.y);
    float v1 = __int_as_float(p1.y);
    acc.x += v0 * x0.x; acc.y += v0 * x0.y; acc.z += v0 * x0.z; acc.w += v0 * x0.w;
    acc.x += v1 * x1.x; acc.y += v1 * x1.y; acc.z += v1 * x1.z; acc.w += v1 * x1.w;
  }
  if (i < end) {
    int2 p0 = pairs[i];
    float4 x0 = *(const float4*)(x + (long)p0.x * 32 + f4 * 4);
    float v0 = __int_as_float(p0.y);
    acc.x += v0 * x0.x; acc.y += v0 * x0.y; acc.z += v0 * x0.z; acc.w += v0 * x0.w;
  }
#pragma unroll
  for (int d = 8; d < 64; d <<= 1) {
    acc.x += __shfl_xor(acc.x, d);
    acc.y += __shfl_xor(acc.y, d);
    acc.z += __shfl_xor(acc.z, d);
    acc.w += __shfl_xor(acc.w, d);
  }
  if (slot == 0) *(float4*)(Tx + (long)wid * 32 + f4 * 4) = acc;
}

// ===== fused gate: weights in LDS (allocator-proof; rounds 9-12: allocator won't
// hold 64-128 per-lane weights). wT[m][k][33]: bank (lane+f)%32, 2-way = free.
__global__ void __launch_bounds__(T256)
gate_lds_kernel(const float* __restrict__ x, const float* __restrict__ Tx,
                const float* __restrict__ Wx0, const float* __restrict__ Wx1,
                const float* __restrict__ bx, const float* __restrict__ bh,
                const float* __restrict__ Wlin, const float* __restrict__ blin,
                float* __restrict__ out, int n) {
  __shared__ float wT[4][2112];
  __shared__ float sb[3][64];
  int tid = threadIdx.x;
  for (int i = tid; i < 8192; i += T256) {
    int m = i >> 11, rem = i & 2047, f = rem >> 6, k = rem & 63;
    const float* src = (m == 0) ? Wx0 : (m == 1) ? Wx1 : (m == 2) ? (Wx0 + 4096) : (Wx1 + 4096);
    wT[m][k * 33 + f] = src[f * 64 + k];
  }
  if (tid < 64) {
    sb[0][tid] = bx[tid] + bh[tid];
    sb[1][tid] = bx[128 + tid] + bh[128 + tid];
    sb[2][tid] = Wlin[tid];
  }
  __syncthreads();

  int lane = tid & 63;
  int wave = blockIdx.x * (T256 / 64) + (tid >> 6);
  int nwaves = gridDim.x * (T256 / 64);
  float bz = sb[0][lane], bt = sb[1][lane], wl = sb[2][lane], bl = blin[0];
  const float* w0 = &wT[0][lane * 33];
  const float* w1 = &wT[1][lane * 33];
  const float* w2 = &wT[2][lane * 33];
  const float* w3 = &wT[3][lane * 33];

  for (int base = wave * 2; base < n; base += nwaves * 2) {
    int node1 = base + 1;
    bool has1 = node1 < n;
    int n1 = has1 ? node1 : base;
    const float4* xp0 = (const float4*)(x + (long)base * 32);
    const float4* tp0 = (const float4*)(Tx + (long)base * 32);
    const float4* xp1 = (const float4*)(x + (long)n1 * 32);
    const float4* tp1 = (const float4*)(Tx + (long)n1 * 32);
    float az0 = bz, at0 = bt, az1 = bz, at1 = bt;
#pragma unroll
    for (int c = 0; c < 8; c++) {
      float4 xa0 = xp0[c], ta0 = tp0[c], xa1 = xp1[c], ta1 = tp1[c];
      int f = c * 4;
      float a, b2, d, g;
      a = w0[f]; b2 = w1[f]; d = w2[f]; g = w3[f];
      az0 += xa0.x * a + ta0.x * b2;  at0 += xa0.x * d + ta0.x * g;
      az1 += xa1.x * a + ta1.x * b2;  at1 += xa1.x * d + ta1.x * g;
      a = w0[f + 1]; b2 = w1[f + 1]; d = w2[f + 1]; g = w3[f + 1];
      az0 += xa0.y * a + ta0.y * b2;  at0 += xa0.y * d + ta0.y * g;
      az1 += xa1.y * a + ta1.y * b2;  at1 += xa1.y * d + ta1.y * g;
      a = w0[f + 2]; b2 = w1[f + 2]; d = w2[f + 2]; g = w3[f + 2];
      az0 += xa0.z * a + ta0.z * b2;  at0 += xa0.z * d + ta0.z * g;
      az1 += xa1.z * a + ta1.z * b2;  at1 += xa1.z * d + ta1.z * g;
      a = w0[f + 3]; b2 = w1[f + 3]; d = w2[f + 3]; g = w3[f + 3];
      az0 += xa0.w * a + ta0.w * b2;  at0 += xa0.w * d + ta0.w * g;
      az1 += xa1.w * a + ta1.w * b2;  at1 += xa1.w * d + ta1.w * g;
    }
    float c0 = __builtin_amdgcn_rcpf(1.0f + __expf(az0)) *
               (1.0f - 2.0f * __builtin_amdgcn_rcpf(__expf(2.0f * at0) + 1.0f)) * wl;
    float c1 = __builtin_amdgcn_rcpf(1.0f + __expf(az1)) *
               (1.0f - 2.0f * __builtin_amdgcn_rcpf(__expf(2.0f * at1) + 1.0f)) * wl;
#pragma unroll
    for (int d = 1; d < 64; d <<= 1) {
      c0 += __shfl_xor(c0, d);
      c1 += __shfl_xor(c1, d);
    }
    if (lane == 0) {
      out[base] = c0 + bl;
      if (has1) out[node1] = c1 + bl;
    }
  }
}

extern "C" void kernel_launch(void* const* d_in, const int* in_sizes, int n_in,
                              void* d_out, int out_size, void* d_ws, size_t ws_size,
                              hipStream_t stream) {
  const float* x    = (const float*)d_in[0];
  const float* ew   = (const float*)d_in[1];
  const float* Wx0  = (const float*)d_in[2];
  const float* Wx1  = (const float*)d_in[3];
  const float* bx   = (const float*)d_in[4];
  const float* bh   = (const float*)d_in[7];
  const float* Wlin = (const float*)d_in[8];
  const float* blin = (const float*)d_in[9];
  const int*   ei   = (const int*)d_in[10];

  int N = in_sizes[0] / 32;
  int E = in_sizes[1];
  const int* row = ei;
  const int* col = ei + E;
  float* out = (float*)d_out;
  long tthreads = (long)N * 64;
  int nR = (N + RANGE - 1) / RANGE;
  int nRB = (N + RANGE_B - 1) / RANGE_B;

  // layout: [Tx 32N (segsum 8N + segd 8N alias)][disq N][startsLoc N][bsum 1024]
  //         [H nB*N][degH∪pairs max(nB*N, 2E)]
  int nBopts[3] = {128, 96, 64};
  int nB = 0;
  size_t wTx = (size_t)N * 32;
  for (int k = 0; k < 3; k++) {
    size_t cb = (size_t)nBopts[k];
    if ((size_t)(E + nBopts[k] - 1) / nBopts[k] > 65535) continue;
    size_t h = cb * N;
    size_t region = h > (size_t)2 * E ? h : (size_t)2 * E;
    size_t tot = wTx + N + N + 1024 + h + region;
    if (tot * 4 <= ws_size) { nB = nBopts[k]; break; }
  }

  if (nB > 0 && N <= 65536) {
    float* Tx     = (float*)d_ws;
    int*   segsum = (int*)Tx;                            // SEG*N ints, dead before gather
    float* segd   = (float*)(segsum + (size_t)SEG * N);  // SEG*N floats, ditto
    float* disq   = Tx + wTx;
    int*   startsLoc = (int*)(disq + N);
    int*   bsum   = startsLoc + N;
    int*   H      = bsum + 1024;
    float* degH   = (float*)(H + (size_t)nB * N);        // aliased with pairs32
    unsigned* pairs32 = (unsigned*)degH;                 // E u32 (region >= 2E words)

    int chunk = (E + nB - 1) / nB;
    int LB = nB / SEG;
    int cblocks = (N + T256 - 1) / T256;

    histcd_kernel<<<dim3(nB, nR), BIG, 0, stream>>>(row, col, ew, H, degH, E, N, chunk);
    colseg1_kernel<<<dim3(cblocks, SEG), T256, 0, stream>>>(H, degH, segsum, segd, N, LB);
    colseg2b_kernel<<<cblocks, T256, 0, stream>>>(segsum, segd, disq, startsLoc, bsum, N);
    scan_top_kernel<<<1, SB, 0, stream>>>(bsum, cblocks);
    colseg3b_kernel<<<dim3(cblocks, SEG), T256, 0, stream>>>(H, segsum, startsLoc, bsum, N, LB);
    bucket2p_kernel<<<dim3(nB, nRB), BIG, 0, stream>>>(row, col, ew, disq, H, pairs32, E, N, chunk);
    // H row 0 now holds the GLOBAL start of each column's bucket
    gatherp_kernel<<<(int)((tthreads + T256 - 1) / T256), T256, 0, stream>>>(
        x, H, pairs32, Tx, N, E);
    gate_lds_kernel<<<1024, T256, 0, stream>>>(x, Tx, Wx0, Wx1, bx, bh, Wlin, blin, out, N);
  } else {
    // legacy: device-scope atomics, int2 pairs
    float* Tx     = (float*)d_ws;
    float* disq   = Tx + wTx;
    int*   starts = (int*)(disq + N);
    int*   bsum   = starts + N;
    int*   H      = bsum + 1024;                    // N counts
    float* degH   = (float*)(H + N);                // N deg
    size_t head = wTx + N + N + 1024 + N + N;
    if (head & 1) head++;
    int2* pairs = (int2*)((float*)d_ws + head);
    int nb1 = (N + SB * ITEMS - 1) / (SB * ITEMS);
    int eb = (E + T256 - 1) / T256;

    zero_kernel<<<256, T256, 0, stream>>>(H, N);
    zero_kernel<<<256, T256, 0, stream>>>((int*)degH, N);
    deghist_dev_kernel<<<eb, T256, 0, stream>>>(ew, row, col, degH, H, E);
    colscan_kernel<<<(N + T256 - 1) / T256, T256, 0, stream>>>(H, degH, disq, starts, N, 1);
    scan1_kernel<<<nb1, SB, 0, stream>>>(starts, bsum, N);
    scan_top_kernel<<<1, SB, 0, stream>>>(bsum, nb1);
    scan_add_kernel<<<(N + T256 - 1) / T256, T256, 0, stream>>>(starts, bsum, N);
    bucket_dev_kernel<<<eb, T256, 0, stream>>>(ew, row, col, disq, starts, pairs, E);
    gather_kernel<<<(int)((tthreads + T256 - 1) / T256), T256, 0, stream>>>(
        x, starts, pairs, Tx, N, E);
    gate_lds_kernel<<<1024, T256, 0, stream>>>(x, Tx, Wx0, Wx1, bx, bh, Wlin, blin, out, N);
  }
}